// Round 4
// baseline (233.935 us; speedup 1.0000x reference)
//
#include <hip/hip_runtime.h>
#include <hip/hip_bf16.h>

typedef float f32x4 __attribute__((ext_vector_type(4)));
typedef short short8 __attribute__((ext_vector_type(8)));

#define MFMA(a, b, c) __builtin_amdgcn_mfma_f32_16x16x32_bf16((a), (b), (c), 0, 0, 0)

#if __has_builtin(__builtin_amdgcn_exp2f)
#define EXP2(x) __builtin_amdgcn_exp2f(x)
#else
#define EXP2(x) exp2f(x)
#endif

#define B_  2
#define N_  2048
#define C_  1024
#define H_  16
#define HD_ 64
#define M_  (B_ * N_)   // 4096

// softmax scale (1/8) * log2(e), folded into Q at qkv epilogue
#define QSCALE 0.18033688011112042f

typedef const __attribute__((address_space(1))) void* gp_t;
typedef __attribute__((address_space(3))) void* sp_t;
#define GLL16(g, s) __builtin_amdgcn_global_load_lds((gp_t)(const void*)(g), (sp_t)(void*)(s), 16, 0, 0)

__device__ __forceinline__ short f2bf(float f) {
    union { float fv; unsigned u; } v; v.fv = f;
    unsigned r = v.u + 0x7fffu + ((v.u >> 16) & 1u);  // RNE
    return (short)(r >> 16);
}

// ---------------- fp32 -> bf16 conversion pass ----------------
__global__ __launch_bounds__(256) void convert_kernel(
    const float* __restrict__ x,  const float* __restrict__ wq,
    const float* __restrict__ wk, const float* __restrict__ wv,
    const float* __restrict__ wo, short* __restrict__ dst)
{
    size_t e = ((size_t)blockIdx.x * 256 + threadIdx.x) * 8;
    const float* src; size_t off;
    if (e < 4194304)      { src = x;  off = e; }
    else if (e < 5242880) { src = wq; off = e - 4194304; }
    else if (e < 6291456) { src = wk; off = e - 5242880; }
    else if (e < 7340032) { src = wv; off = e - 6291456; }
    else                  { src = wo; off = e - 7340032; }
    float4 a = *(const float4*)(src + off);
    float4 b = *(const float4*)(src + off + 4);
    short8 s;
    s[0] = f2bf(a.x); s[1] = f2bf(a.y); s[2] = f2bf(a.z); s[3] = f2bf(a.w);
    s[4] = f2bf(b.x); s[5] = f2bf(b.y); s[6] = f2bf(b.z); s[7] = f2bf(b.w);
    *(short8*)(dst + e) = s;
}

// ---------------- fused QKV GEMM ----------------
// 128x128 tile, BK=32, global_load_lds staging. Q gets QSCALE folded.
// For V blocks the fragment sources are swapped so C^T comes out and the
// transposed Vt store is ns-contiguous (32B segments, not 4KB-stride scatter).
__global__ __launch_bounds__(256) void qkv_gemm(
    const short* __restrict__ xb, const short* __restrict__ Wb,
    short* __restrict__ Qb, short* __restrict__ Kb, short* __restrict__ Vt)
{
    const int m0 = blockIdx.x * 128;
    const int n0 = blockIdx.y * 128;
    __shared__ short As[128 * 32];
    __shared__ short Bs[128 * 32];
    const int tid  = threadIdx.x;
    const int wave = tid >> 6, lane = tid & 63;
    const int quad = lane >> 4, l16 = lane & 15;
    const int wr = (wave >> 1) * 64, wc = (wave & 1) * 64;
    const int which = n0 >> 10;        // block-uniform: 0=Q 1=K 2=V

    const short* Fa = (which == 2) ? Bs : As;   // rows of C
    const short* Fb = (which == 2) ? As : Bs;   // cols of C

    f32x4 acc[4][4] = {};

    for (int kk = 0; kk < C_; kk += 32) {
        __syncthreads();
        #pragma unroll
        for (int it = 0; it < 2; ++it) {
            int f = (it * 256 + tid) * 8;
            int row = f >> 5, col = f & 31;
            GLL16(xb + (size_t)(m0 + row) * C_ + kk + col, &As[f]);
            GLL16(Wb + (size_t)(n0 + row) * C_ + kk + col, &Bs[f]);
        }
        __syncthreads();
        short8 af[4], bf[4];
        #pragma unroll
        for (int mi = 0; mi < 4; ++mi) af[mi] = *(const short8*)&Fa[(wr + mi * 16 + l16) * 32 + quad * 8];
        #pragma unroll
        for (int ni = 0; ni < 4; ++ni) bf[ni] = *(const short8*)&Fb[(wc + ni * 16 + l16) * 32 + quad * 8];
        #pragma unroll
        for (int mi = 0; mi < 4; ++mi)
        #pragma unroll
        for (int ni = 0; ni < 4; ++ni)
            acc[mi][ni] = MFMA(af[mi], bf[ni], acc[mi][ni]);
    }

    const int nb = n0 & 1023;
    if (which == 2) {
        // C^T: row = n-dim (W rows), col = m-dim
        #pragma unroll
        for (int mi = 0; mi < 4; ++mi)
        #pragma unroll
        for (int ni = 0; ni < 4; ++ni)
        #pragma unroll
        for (int r = 0; r < 4; ++r) {
            int cc = nb + wr + mi * 16 + quad * 4 + r;
            int m  = m0 + wc + ni * 16 + l16;
            int bb = m >> 11, ns = m & (N_ - 1);
            int h = cc >> 6, d = cc & 63;
            Vt[(((size_t)(bb * H_ + h)) * HD_ + d) * N_ + ns] = f2bf(acc[mi][ni][r]);
        }
    } else {
        #pragma unroll
        for (int mi = 0; mi < 4; ++mi)
        #pragma unroll
        for (int ni = 0; ni < 4; ++ni)
        #pragma unroll
        for (int r = 0; r < 4; ++r) {
            int m  = m0 + wr + mi * 16 + quad * 4 + r;
            int cc = nb + wc + ni * 16 + l16;
            float av = acc[mi][ni][r];
            if (which == 0) av *= QSCALE;
            short bv = f2bf(av);
            int bb = m >> 11, ns = m & (N_ - 1);
            int h = cc >> 6, d = cc & 63;
            size_t bh = (size_t)(bb * H_ + h);
            if (which == 0) Qb[(bh * N_ + ns) * HD_ + d] = bv;
            else            Kb[(bh * N_ + ns) * HD_ + d] = bv;
        }
    }
}

// ---------------- Flash attention ----------------
// grid (N/128, B*H), block 256 (4 waves), 2x16-row Q strips per wave.
// S^T = MFMA(A=K, B=Q); P packed b64 into Ps[i][j] (aliases Qs);
// PV via K=32 MFMA (A=P frag b128, B=V^T frag b128). XOR-swizzled LDS,
// register-prefetched K/V staging.
__global__ __launch_bounds__(256, 2) void attn_kernel(
    const short* __restrict__ Qb, const short* __restrict__ Kb,
    const short* __restrict__ Vt, short* __restrict__ Ob)
{
    const int bh = blockIdx.y;
    const int b = bh >> 4, h = bh & (H_ - 1);
    const int i0 = blockIdx.x * 128;
    __shared__ short Qs[128 * 64];  // 16 KB; reused as Ps[i][j] after prologue
    __shared__ short Ks[64 * 64];   //  8 KB
    __shared__ short Vs[64 * 64];   //  8 KB, Vs[d][j]
    short* const Ps = Qs;
    const int tid  = threadIdx.x;
    const int wave = tid >> 6, lane = tid & 63;
    const int quad = lane >> 4, l16 = lane & 15;
    const int sw = l16 & 7;         // swizzle key: 16B chunk c -> c ^ (row&7), row&7 == l16&7 for all frag reads

    const short* Qg = Qb + ((size_t)bh * N_ + i0) * HD_;
    const short* Kg = Kb + (size_t)bh * N_ * HD_;
    const short* Vg = Vt + (size_t)bh * HD_ * N_;

    #pragma unroll
    for (int it = 0; it < 4; ++it) {
        int e = tid + it * 256;          // 1024 uint4 for 128x64 Q tile
        int row = e >> 3, c8 = e & 7;
        *(uint4*)&Qs[row * 64 + ((c8 ^ (row & 7)) * 8)] = *(const uint4*)(Qg + row * HD_ + c8 * 8);
    }
    __syncthreads();
    short8 qf[2][2];
    #pragma unroll
    for (int s = 0; s < 2; ++s) {
        int row = (wave * 32 + s * 16 + l16) * 64;
        qf[s][0] = *(const short8*)&Qs[row + ((quad ^ sw) * 8)];
        qf[s][1] = *(const short8*)&Qs[row + (((quad + 4) ^ sw) * 8)];
    }
    __syncthreads();   // everyone done reading Qs before it becomes Ps

    f32x4 o[2][4] = {};
    float lrow[2] = {0.f, 0.f};

    uint4 kr[2], vr[2];
    #pragma unroll
    for (int it = 0; it < 2; ++it) {
        int e = tid + it * 256, row = e >> 3, c8 = e & 7;
        kr[it] = *(const uint4*)(Kg + (size_t)row * HD_ + c8 * 8);
        vr[it] = *(const uint4*)(Vg + (size_t)row * N_ + c8 * 8);
    }

    for (int j0 = 0; j0 < N_; j0 += 64) {
        __syncthreads();   // all waves done reading Ks/Vs of previous tile
        #pragma unroll
        for (int it = 0; it < 2; ++it) {
            int e = tid + it * 256, row = e >> 3, c8 = e & 7;
            int sc = (c8 ^ (row & 7)) * 8;
            *(uint4*)&Ks[row * 64 + sc] = kr[it];
            *(uint4*)&Vs[row * 64 + sc] = vr[it];
        }
        if (j0 + 64 < N_) {
            #pragma unroll
            for (int it = 0; it < 2; ++it) {
                int e = tid + it * 256, row = e >> 3, c8 = e & 7;
                kr[it] = *(const uint4*)(Kg + (size_t)(j0 + 64 + row) * HD_ + c8 * 8);
                vr[it] = *(const uint4*)(Vg + (size_t)row * N_ + j0 + 64 + c8 * 8);
            }
        }
        __syncthreads();

        // S^T + exp + pack P into LDS
        #pragma unroll
        for (int ni = 0; ni < 4; ++ni) {
            int krow = (ni * 16 + l16) * 64;
            short8 kf0 = *(const short8*)&Ks[krow + ((quad ^ sw) * 8)];
            short8 kf1 = *(const short8*)&Ks[krow + (((quad + 4) ^ sw) * 8)];
            #pragma unroll
            for (int s = 0; s < 2; ++s) {
                f32x4 st = {0.f, 0.f, 0.f, 0.f};
                st = MFMA(kf0, qf[s][0], st);
                st = MFMA(kf1, qf[s][1], st);   // S^T[j=ni*16+quad*4+r][i=strip+l16]
                union { float f; unsigned u; } c0, c1, c2, c3;
                c0.f = EXP2(st[0]); c1.f = EXP2(st[1]);
                c2.f = EXP2(st[2]); c3.f = EXP2(st[3]);
                lrow[s] += (c0.f + c1.f) + (c2.f + c3.f);
                unsigned w0 = (c0.u >> 16) | (c1.u & 0xffff0000u);
                unsigned w1 = (c2.u >> 16) | (c3.u & 0xffff0000u);
                int irow = (wave * 32 + s * 16 + l16) * 64;
                int chunk = (ni * 2 + (quad >> 1)) ^ sw;
                *(uint2*)&Ps[irow + chunk * 8 + (quad & 1) * 4] = make_uint2(w0, w1);
            }
        }

        // O[i][d] += P[i][j] V[j][d]  (K=32 MFMA; in-wave lgkm orders Ps write->read)
        #pragma unroll
        for (int ks = 0; ks < 2; ++ks) {
            int kc = ((ks * 4 + quad) ^ sw) * 8;
            short8 vfr[4];
            #pragma unroll
            for (int di = 0; di < 4; ++di)
                vfr[di] = *(const short8*)&Vs[(di * 16 + l16) * 64 + kc];
            #pragma unroll
            for (int s = 0; s < 2; ++s) {
                short8 pf = *(const short8*)&Ps[(wave * 32 + s * 16 + l16) * 64 + kc];
                #pragma unroll
                for (int di = 0; di < 4; ++di)
                    o[s][di] = MFMA(pf, vfr[di], o[s][di]);
            }
        }
    }

    #pragma unroll
    for (int s = 0; s < 2; ++s) {
        float l = lrow[s];
        l += __shfl_xor(l, 16, 64);
        l += __shfl_xor(l, 32, 64);      // full row-sum for i=l16, all quads
        #pragma unroll
        for (int r = 0; r < 4; ++r) {
            float inv = 1.f / __shfl(l, quad * 4 + r, 64);
            int ig = i0 + wave * 32 + s * 16 + quad * 4 + r;
            size_t base = ((size_t)(b * N_ + ig)) * C_ + h * HD_;
            #pragma unroll
            for (int di = 0; di < 4; ++di)
                Ob[base + di * 16 + l16] = f2bf(o[s][di][r] * inv);
        }
    }
}

// ---------------- Output projection ----------------
__global__ __launch_bounds__(256) void proj_gemm(
    const short* __restrict__ Ob, const short* __restrict__ wob,
    const float* __restrict__ bo, float* __restrict__ out)
{
    const int m0 = blockIdx.x * 64;
    const int n0 = blockIdx.y * 128;
    __shared__ short As[64 * 32];
    __shared__ short Bs[128 * 32];
    const int tid  = threadIdx.x;
    const int wave = tid >> 6, lane = tid & 63;
    const int quad = lane >> 4, l16 = lane & 15;
    const int wr = (wave >> 1) * 32, wc = (wave & 1) * 64;

    f32x4 acc[2][4] = {};

    for (int kk = 0; kk < C_; kk += 32) {
        __syncthreads();
        {
            int f = tid * 8;
            int row = f >> 5, col = f & 31;
            GLL16(Ob + (size_t)(m0 + row) * C_ + kk + col, &As[f]);
        }
        #pragma unroll
        for (int it = 0; it < 2; ++it) {
            int f = (it * 256 + tid) * 8;
            int row = f >> 5, col = f & 31;
            GLL16(wob + (size_t)(n0 + row) * C_ + kk + col, &Bs[f]);
        }
        __syncthreads();
        short8 af[2], bf[4];
        #pragma unroll
        for (int mi = 0; mi < 2; ++mi) af[mi] = *(const short8*)&As[(wr + mi * 16 + l16) * 32 + quad * 8];
        #pragma unroll
        for (int ni = 0; ni < 4; ++ni) bf[ni] = *(const short8*)&Bs[(wc + ni * 16 + l16) * 32 + quad * 8];
        #pragma unroll
        for (int mi = 0; mi < 2; ++mi)
        #pragma unroll
        for (int ni = 0; ni < 4; ++ni)
            acc[mi][ni] = MFMA(af[mi], bf[ni], acc[mi][ni]);
    }

    #pragma unroll
    for (int mi = 0; mi < 2; ++mi)
    #pragma unroll
    for (int ni = 0; ni < 4; ++ni)
    #pragma unroll
    for (int r = 0; r < 4; ++r) {
        int m = m0 + wr + mi * 16 + quad * 4 + r;
        int c = n0 + wc + ni * 16 + l16;
        out[(size_t)m * C_ + c] = acc[mi][ni][r] + bo[c];
    }
}

extern "C" void kernel_launch(void* const* d_in, const int* in_sizes, int n_in,
                              void* d_out, int out_size, void* d_ws, size_t ws_size,
                              hipStream_t stream) {
    const float* x  = (const float*)d_in[0];
    const float* wq = (const float*)d_in[1];
    const float* wk = (const float*)d_in[2];
    const float* wv = (const float*)d_in[3];
    const float* wo = (const float*)d_in[4];
    const float* bo = (const float*)d_in[5];
    float* out = (float*)d_out;

    short* xb  = (short*)d_ws;        // 4M shorts
    short* Wb  = xb  + 4194304;       // 3M (wq|wk|wv)
    short* wob = Wb  + 3145728;       // 1M
    short* Qb  = wob + 1048576;       // 4M
    short* Kb  = Qb  + 4194304;       // 4M
    short* Vt  = Kb  + 4194304;       // 4M
    short* Obuf= Vt  + 4194304;       // 4M

    dim3 blk(256);
    convert_kernel<<<4096, blk, 0, stream>>>(x, wq, wk, wv, wo, xb);
    qkv_gemm<<<dim3(M_ / 128, 3072 / 128), blk, 0, stream>>>(xb, Wb, Qb, Kb, Vt);
    attn_kernel<<<dim3(N_ / 128, B_ * H_), blk, 0, stream>>>(Qb, Kb, Vt, Obuf);
    proj_gemm<<<dim3(M_ / 64, C_ / 128), blk, 0, stream>>>(Obuf, wob, bo, out);
}